// Round 6
// baseline (109.222 us; speedup 1.0000x reference)
//
#include <hip/hip_runtime.h>
#include <cstddef>
#include <cstdint>

constexpr int BATCH   = 4096;
constexpr int IN_DIM  = 8192;
constexpr int OUT_DIM = 16384;
constexpr int THREADS = 256;                        // 4 waves per block
constexpr int NBLK    = BATCH / 2;                  // 2048 blocks, one row-pair each
constexpr int OPT     = 4;                          // outputs per thread per iter
constexpr int ITERS   = OUT_DIM / (THREADS * OPT);  // 16
constexpr int SSTEPS  = (IN_DIM / 4) / THREADS;     // 8 staging steps (f32x4 per row)

typedef float    f32x4 __attribute__((ext_vector_type(4)));
typedef uint32_t u32x4 __attribute__((ext_vector_type(4)));

__device__ __forceinline__ uint32_t f2bf(float f) {   // RNE bf16 (x in [0,1), no NaN)
  uint32_t u = __float_as_uint(f);
  u += 0x7fffu + ((u >> 16) & 1u);
  return u >> 16;
}
__device__ __forceinline__ uint32_t pack_bf(float a, float b) {
  return f2bf(a) | (f2bf(b) << 16);
}
__device__ __forceinline__ float bf_lo(uint32_t u) { return __uint_as_float(u << 16); }
__device__ __forceinline__ float bf_hi(uint32_t u) { return __uint_as_float(u & 0xffff0000u); }

// softmax over 16 gate logits collapsed to (c0, ca, cb, cab); also packs idx pair
__global__ __launch_bounds__(64)
void coef_kernel(const float* __restrict__ weights,
                 const int* __restrict__ idx_a,
                 const int* __restrict__ idx_b,
                 float4* __restrict__ coef,
                 uint32_t* __restrict__ pidx) {
  const int o = blockIdx.x * 64 + threadIdx.x;
  if (o >= OUT_DIM) return;

  const float4* wp = reinterpret_cast<const float4*>(weights + (size_t)o * 16);
  float4 t0 = wp[0], t1 = wp[1], t2 = wp[2], t3 = wp[3];
  float w[16] = { t0.x, t0.y, t0.z, t0.w, t1.x, t1.y, t1.z, t1.w,
                  t2.x, t2.y, t2.z, t2.w, t3.x, t3.y, t3.z, t3.w };
  float m = w[0];
#pragma unroll
  for (int i = 1; i < 16; ++i) m = fmaxf(m, w[i]);
  float p[16]; float s = 0.f;
#pragma unroll
  for (int i = 0; i < 16; ++i) { p[i] = __expf(w[i] - m); s += p[i]; }
  const float inv = 1.0f / s;
  const float GC[16]  = {0,0,0,0, 0,0,0,0, 1,1,1,1, 1,1,1,1};
  const float GA[16]  = {0,0,1,1, 0,0,1,1, -1,-1,0,0, -1,-1,0,0};
  const float GB[16]  = {0,0,0,0, 1,1,1,1, -1,-1,-1,-1, 0,0,0,0};
  const float GAB[16] = {0,1,-1,0, -1,0,-2,-1, 1,2,0,1, 0,1,-1,0};
  float c0 = 0.f, ca = 0.f, cb = 0.f, cab = 0.f;
#pragma unroll
  for (int i = 0; i < 16; ++i) {
    c0 += p[i] * GC[i]; ca += p[i] * GA[i];
    cb += p[i] * GB[i]; cab += p[i] * GAB[i];
  }
  coef[o] = make_float4(c0 * inv, ca * inv, cb * inv, cab * inv);
  pidx[o] = (uint32_t)idx_a[o] | ((uint32_t)idx_b[o] << 16);
}

__global__ __launch_bounds__(THREADS)
void logic_main(const float* __restrict__ x,
                const float4* __restrict__ coef,
                const uint32_t* __restrict__ pidx,
                float* __restrict__ out) {
  // xp[i] = { bf16 x[b0][i] (lo), bf16 x[b1][i] (hi) } -> 32 KB, 5 blocks/CU
  __shared__ uint32_t xp[IN_DIM];

  const int t  = threadIdx.x;
  const int b0 = blockIdx.x * 2;

  const f32x4* __restrict__ r0 =
      reinterpret_cast<const f32x4*>(x + (size_t)b0 * IN_DIM);
  const f32x4* __restrict__ r1 =
      reinterpret_cast<const f32x4*>(x + (size_t)(b0 + 1) * IN_DIM);

  // ---- stage row-pair as packed bf16 (plain loads: through L2) ----
#pragma unroll
  for (int s = 0; s < SSTEPS; ++s) {
    const int q = s * THREADS + t;                 // f32x4 index (elements 4q..4q+3)
    f32x4 a = r0[q];
    f32x4 b = r1[q];
    u32x4 pk;
    pk.x = pack_bf(a.x, b.x);
    pk.y = pack_bf(a.y, b.y);
    pk.z = pack_bf(a.z, b.z);
    pk.w = pack_bf(a.w, b.w);
    *reinterpret_cast<u32x4*>(&xp[4 * q]) = pk;    // ds_write_b128
  }
  __syncthreads();

#pragma unroll 4
  for (int it = 0; it < ITERS; ++it) {
    const int o = it * (THREADS * OPT) + t * OPT;

    const int4 pi = *reinterpret_cast<const int4*>(pidx + o);
    const float4 c0 = coef[o + 0], c1 = coef[o + 1],
                 c2 = coef[o + 2], c3 = coef[o + 3];

    // one ds_read_b32 per operand serves BOTH rows (bf16 pair)
    const uint32_t ga0 = xp[(uint32_t)pi.x & 0xffffu], gb0 = xp[(uint32_t)pi.x >> 16];
    const uint32_t ga1 = xp[(uint32_t)pi.y & 0xffffu], gb1 = xp[(uint32_t)pi.y >> 16];
    const uint32_t ga2 = xp[(uint32_t)pi.z & 0xffffu], gb2 = xp[(uint32_t)pi.z >> 16];
    const uint32_t ga3 = xp[(uint32_t)pi.w & 0xffffu], gb3 = xp[(uint32_t)pi.w >> 16];

    f32x4 res0, res1;
    {
      const float a0 = bf_lo(ga0), b0v = bf_lo(gb0);
      const float a1 = bf_hi(ga0), b1v = bf_hi(gb0);
      res0.x = fmaf(fmaf(c0.w, a0, c0.z), b0v, fmaf(c0.y, a0, c0.x));
      res1.x = fmaf(fmaf(c0.w, a1, c0.z), b1v, fmaf(c0.y, a1, c0.x));
    }
    {
      const float a0 = bf_lo(ga1), b0v = bf_lo(gb1);
      const float a1 = bf_hi(ga1), b1v = bf_hi(gb1);
      res0.y = fmaf(fmaf(c1.w, a0, c1.z), b0v, fmaf(c1.y, a0, c1.x));
      res1.y = fmaf(fmaf(c1.w, a1, c1.z), b1v, fmaf(c1.y, a1, c1.x));
    }
    {
      const float a0 = bf_lo(ga2), b0v = bf_lo(gb2);
      const float a1 = bf_hi(ga2), b1v = bf_hi(gb2);
      res0.z = fmaf(fmaf(c2.w, a0, c2.z), b0v, fmaf(c2.y, a0, c2.x));
      res1.z = fmaf(fmaf(c2.w, a1, c2.z), b1v, fmaf(c2.y, a1, c2.x));
    }
    {
      const float a0 = bf_lo(ga3), b0v = bf_lo(gb3);
      const float a1 = bf_hi(ga3), b1v = bf_hi(gb3);
      res0.w = fmaf(fmaf(c3.w, a0, c3.z), b0v, fmaf(c3.y, a0, c3.x));
      res1.w = fmaf(fmaf(c3.w, a1, c3.z), b1v, fmaf(c3.y, a1, c3.x));
    }

    // plain stores: stream through L2 (same path as the 6.9 TB/s fill kernels)
    *reinterpret_cast<f32x4*>(out + (size_t)b0 * OUT_DIM + o) = res0;
    *reinterpret_cast<f32x4*>(out + (size_t)(b0 + 1) * OUT_DIM + o) = res1;
  }
}

extern "C" void kernel_launch(void* const* d_in, const int* in_sizes, int n_in,
                              void* d_out, int out_size, void* d_ws, size_t ws_size,
                              hipStream_t stream) {
  const float* x       = (const float*)d_in[0];
  const float* weights = (const float*)d_in[1];
  const int*   idx_a   = (const int*)d_in[2];
  const int*   idx_b   = (const int*)d_in[3];
  float*       out     = (float*)d_out;

  float4*   coef = (float4*)d_ws;                         // 256 KB
  uint32_t* pidx = (uint32_t*)((char*)d_ws + (size_t)OUT_DIM * 16);  // +64 KB

  coef_kernel<<<OUT_DIM / 64, 64, 0, stream>>>(weights, idx_a, idx_b, coef, pidx);
  logic_main<<<NBLK, THREADS, 0, stream>>>(x, coef, pidx, out);
}

// Round 8
// 100.674 us; speedup vs baseline: 1.0849x; 1.0849x over previous
//
#include <hip/hip_runtime.h>
#include <cstddef>
#include <cstdint>

constexpr int BATCH   = 4096;
constexpr int IN_DIM  = 8192;
constexpr int OUT_DIM = 16384;
constexpr int THREADS = 512;                        // 8 waves per block
constexpr int RPB     = 4;                          // batch rows per block
constexpr int NBLK    = BATCH / RPB;                // 1024 blocks
constexpr int OPT     = 4;                          // neurons per thread per chunk
constexpr int CHUNKS  = OUT_DIM / (THREADS * OPT);  // 8
constexpr int SSTEPS  = (IN_DIM / 4) / THREADS;     // 4 staging steps (f32x4 per row)

typedef float    f32x4 __attribute__((ext_vector_type(4)));
typedef uint32_t u32x4 __attribute__((ext_vector_type(4)));

__device__ __forceinline__ uint32_t f2bf(float f) {   // RNE bf16 (x in [0,1))
  uint32_t u = __float_as_uint(f);
  u += 0x7fffu + ((u >> 16) & 1u);
  return u >> 16;
}
__device__ __forceinline__ uint32_t pack_bf(float a, float b) {
  return f2bf(a) | (f2bf(b) << 16);
}
__device__ __forceinline__ float bf_lo(uint32_t u) { return __uint_as_float(u << 16); }
__device__ __forceinline__ float bf_hi(uint32_t u) { return __uint_as_float(u & 0xffff0000u); }

// softmax over 16 gate logits collapsed to (c0, ca, cb, cab); also packs idx pair
__global__ __launch_bounds__(64)
void coef_kernel(const float* __restrict__ weights,
                 const int* __restrict__ idx_a,
                 const int* __restrict__ idx_b,
                 float4* __restrict__ coef,
                 uint32_t* __restrict__ pidx) {
  const int o = blockIdx.x * 64 + threadIdx.x;
  if (o >= OUT_DIM) return;

  const float4* wp = reinterpret_cast<const float4*>(weights + (size_t)o * 16);
  float4 t0 = wp[0], t1 = wp[1], t2 = wp[2], t3 = wp[3];
  float w[16] = { t0.x, t0.y, t0.z, t0.w, t1.x, t1.y, t1.z, t1.w,
                  t2.x, t2.y, t2.z, t2.w, t3.x, t3.y, t3.z, t3.w };
  float m = w[0];
#pragma unroll
  for (int i = 1; i < 16; ++i) m = fmaxf(m, w[i]);
  float p[16]; float s = 0.f;
#pragma unroll
  for (int i = 0; i < 16; ++i) { p[i] = __expf(w[i] - m); s += p[i]; }
  const float inv = 1.0f / s;
  const float GC[16]  = {0,0,0,0, 0,0,0,0, 1,1,1,1, 1,1,1,1};
  const float GA[16]  = {0,0,1,1, 0,0,1,1, -1,-1,0,0, -1,-1,0,0};
  const float GB[16]  = {0,0,0,0, 1,1,1,1, -1,-1,-1,-1, 0,0,0,0};
  const float GAB[16] = {0,1,-1,0, -1,0,-2,-1, 1,2,0,1, 0,1,-1,0};
  float c0 = 0.f, ca = 0.f, cb = 0.f, cab = 0.f;
#pragma unroll
  for (int i = 0; i < 16; ++i) {
    c0 += p[i] * GC[i]; ca += p[i] * GA[i];
    cb += p[i] * GB[i]; cab += p[i] * GAB[i];
  }
  coef[o] = make_float4(c0 * inv, ca * inv, cb * inv, cab * inv);
  pidx[o] = (uint32_t)idx_a[o] | ((uint32_t)idx_b[o] << 16);
}

// 2-row affine eval from one packed gather pair; returns {lo-row, hi-row}
__device__ __forceinline__ float2 eval2(float4 c, uint32_t ga, uint32_t gb) {
  const float a0 = bf_lo(ga), b0 = bf_lo(gb);
  const float a1 = bf_hi(ga), b1 = bf_hi(gb);
  float2 r;
  r.x = fmaf(fmaf(c.w, a0, c.z), b0, fmaf(c.y, a0, c.x));
  r.y = fmaf(fmaf(c.w, a1, c.z), b1, fmaf(c.y, a1, c.x));
  return r;
}

__global__ __launch_bounds__(THREADS)
void logic_main(const float* __restrict__ x,
                const float4* __restrict__ coef,
                const uint32_t* __restrict__ pidx,
                float* __restrict__ out) {
  // two pair-packed row buffers: A = rows (b0, b0+1), B = rows (b0+2, b0+3)
  __shared__ uint32_t xpA[IN_DIM];                  // 32 KB
  __shared__ uint32_t xpB[IN_DIM];                  // 32 KB  -> 64 KB total, 2 blocks/CU

  const int t  = threadIdx.x;
  const int b0 = blockIdx.x * RPB;

  const f32x4* __restrict__ r0 =
      reinterpret_cast<const f32x4*>(x + (size_t)(b0 + 0) * IN_DIM);
  const f32x4* __restrict__ r1 =
      reinterpret_cast<const f32x4*>(x + (size_t)(b0 + 1) * IN_DIM);
  const f32x4* __restrict__ r2 =
      reinterpret_cast<const f32x4*>(x + (size_t)(b0 + 2) * IN_DIM);
  const f32x4* __restrict__ r3 =
      reinterpret_cast<const f32x4*>(x + (size_t)(b0 + 3) * IN_DIM);

  // prefetch chunk-0 operands (hide L2 latency under staging)
  int o0 = t * OPT;
  int4   pi = *reinterpret_cast<const int4*>(pidx + o0);
  float4 c0 = coef[o0 + 0], c1 = coef[o0 + 1],
         c2 = coef[o0 + 2], c3 = coef[o0 + 3];

  // ---- stage 4 rows as two pair-packed bf16 arrays ----
#pragma unroll
  for (int s = 0; s < SSTEPS; ++s) {
    const int q = s * THREADS + t;                  // f32x4 index
    f32x4 a = r0[q], b = r1[q];
    u32x4 pkA;
    pkA.x = pack_bf(a.x, b.x); pkA.y = pack_bf(a.y, b.y);
    pkA.z = pack_bf(a.z, b.z); pkA.w = pack_bf(a.w, b.w);
    *reinterpret_cast<u32x4*>(&xpA[4 * q]) = pkA;
    f32x4 c = r2[q], d = r3[q];
    u32x4 pkB;
    pkB.x = pack_bf(c.x, d.x); pkB.y = pack_bf(c.y, d.y);
    pkB.z = pack_bf(c.z, d.z); pkB.w = pack_bf(c.w, d.w);
    *reinterpret_cast<u32x4*>(&xpB[4 * q]) = pkB;
  }
  __syncthreads();

#pragma unroll 2
  for (int ch = 0; ch < CHUNKS; ++ch) {
    const int o = ch * (THREADS * OPT) + t * OPT;

    const uint32_t i0a = (uint32_t)pi.x & 0xffffu, i0b = (uint32_t)pi.x >> 16;
    const uint32_t i1a = (uint32_t)pi.y & 0xffffu, i1b = (uint32_t)pi.y >> 16;
    const uint32_t i2a = (uint32_t)pi.z & 0xffffu, i2b = (uint32_t)pi.z >> 16;
    const uint32_t i3a = (uint32_t)pi.w & 0xffffu, i3b = (uint32_t)pi.w >> 16;

    // 16 gathers: one ds_read_b32 serves two rows
    const uint32_t gA0a = xpA[i0a], gA0b = xpA[i0b];
    const uint32_t gA1a = xpA[i1a], gA1b = xpA[i1b];
    const uint32_t gA2a = xpA[i2a], gA2b = xpA[i2b];
    const uint32_t gA3a = xpA[i3a], gA3b = xpA[i3b];
    const uint32_t gB0a = xpB[i0a], gB0b = xpB[i0b];
    const uint32_t gB1a = xpB[i1a], gB1b = xpB[i1b];
    const uint32_t gB2a = xpB[i2a], gB2b = xpB[i2b];
    const uint32_t gB3a = xpB[i3a], gB3b = xpB[i3b];

    const float2 e00 = eval2(c0, gA0a, gA0b);
    const float2 e01 = eval2(c1, gA1a, gA1b);
    const float2 e02 = eval2(c2, gA2a, gA2b);
    const float2 e03 = eval2(c3, gA3a, gA3b);
    const float2 e10 = eval2(c0, gB0a, gB0b);
    const float2 e11 = eval2(c1, gB1a, gB1b);
    const float2 e12 = eval2(c2, gB2a, gB2b);
    const float2 e13 = eval2(c3, gB3a, gB3b);

    f32x4 res0, res1, res2, res3;
    res0.x = e00.x; res0.y = e01.x; res0.z = e02.x; res0.w = e03.x;
    res1.x = e00.y; res1.y = e01.y; res1.z = e02.y; res1.w = e03.y;
    res2.x = e10.x; res2.y = e11.x; res2.z = e12.x; res2.w = e13.x;
    res3.x = e10.y; res3.y = e11.y; res3.z = e12.y; res3.w = e13.y;

    // prefetch next chunk's operands before the stores
    if (ch + 1 < CHUNKS) {
      const int on = o + THREADS * OPT;
      pi = *reinterpret_cast<const int4*>(pidx + on);
      c0 = coef[on + 0]; c1 = coef[on + 1];
      c2 = coef[on + 2]; c3 = coef[on + 3];
    }

    *reinterpret_cast<f32x4*>(out + (size_t)(b0 + 0) * OUT_DIM + o) = res0;
    *reinterpret_cast<f32x4*>(out + (size_t)(b0 + 1) * OUT_DIM + o) = res1;
    *reinterpret_cast<f32x4*>(out + (size_t)(b0 + 2) * OUT_DIM + o) = res2;
    *reinterpret_cast<f32x4*>(out + (size_t)(b0 + 3) * OUT_DIM + o) = res3;
  }
}

extern "C" void kernel_launch(void* const* d_in, const int* in_sizes, int n_in,
                              void* d_out, int out_size, void* d_ws, size_t ws_size,
                              hipStream_t stream) {
  const float* x       = (const float*)d_in[0];
  const float* weights = (const float*)d_in[1];
  const int*   idx_a   = (const int*)d_in[2];
  const int*   idx_b   = (const int*)d_in[3];
  float*       out     = (float*)d_out;

  float4*   coef = (float4*)d_ws;                                   // 256 KB
  uint32_t* pidx = (uint32_t*)((char*)d_ws + (size_t)OUT_DIM * 16); // +64 KB

  coef_kernel<<<OUT_DIM / 64, 64, 0, stream>>>(weights, idx_a, idx_b, coef, pidx);
  logic_main<<<NBLK, THREADS, 0, stream>>>(x, coef, pidx, out);
}

// Round 9
// 97.606 us; speedup vs baseline: 1.1190x; 1.0314x over previous
//
#include <hip/hip_runtime.h>
#include <cstddef>
#include <cstdint>

constexpr int BATCH   = 4096;
constexpr int IN_DIM  = 8192;
constexpr int OUT_DIM = 16384;
constexpr int THREADS = 512;                        // 8 waves per block
constexpr int RPB     = 4;                          // batch rows per block
constexpr int NBLK    = BATCH / RPB;                // 1024 blocks
constexpr int OPT     = 4;                          // neurons per thread per chunk
constexpr int CHUNKS  = OUT_DIM / (THREADS * OPT);  // 8
constexpr int SSTEPS  = (IN_DIM / 4) / THREADS;     // 4 staging steps (f32x4 per row)

typedef float    f32x4 __attribute__((ext_vector_type(4)));
typedef uint32_t u32x2 __attribute__((ext_vector_type(2)));

__device__ __forceinline__ uint32_t f2bf(float f) {   // RNE bf16 (x in [0,1))
  uint32_t u = __float_as_uint(f);
  u += 0x7fffu + ((u >> 16) & 1u);
  return u >> 16;
}
__device__ __forceinline__ uint32_t pack_bf(float a, float b) {
  return f2bf(a) | (f2bf(b) << 16);
}
__device__ __forceinline__ float bf_lo(uint32_t u) { return __uint_as_float(u << 16); }
__device__ __forceinline__ float bf_hi(uint32_t u) { return __uint_as_float(u & 0xffff0000u); }

// softmax over 16 gate logits collapsed to (c0, ca, cb, cab); also packs idx pair
__global__ __launch_bounds__(64)
void coef_kernel(const float* __restrict__ weights,
                 const int* __restrict__ idx_a,
                 const int* __restrict__ idx_b,
                 float4* __restrict__ coef,
                 uint32_t* __restrict__ pidx) {
  const int o = blockIdx.x * 64 + threadIdx.x;
  if (o >= OUT_DIM) return;

  const float4* wp = reinterpret_cast<const float4*>(weights + (size_t)o * 16);
  float4 t0 = wp[0], t1 = wp[1], t2 = wp[2], t3 = wp[3];
  float w[16] = { t0.x, t0.y, t0.z, t0.w, t1.x, t1.y, t1.z, t1.w,
                  t2.x, t2.y, t2.z, t2.w, t3.x, t3.y, t3.z, t3.w };
  float m = w[0];
#pragma unroll
  for (int i = 1; i < 16; ++i) m = fmaxf(m, w[i]);
  float p[16]; float s = 0.f;
#pragma unroll
  for (int i = 0; i < 16; ++i) { p[i] = __expf(w[i] - m); s += p[i]; }
  const float inv = 1.0f / s;
  const float GC[16]  = {0,0,0,0, 0,0,0,0, 1,1,1,1, 1,1,1,1};
  const float GA[16]  = {0,0,1,1, 0,0,1,1, -1,-1,0,0, -1,-1,0,0};
  const float GB[16]  = {0,0,0,0, 1,1,1,1, -1,-1,-1,-1, 0,0,0,0};
  const float GAB[16] = {0,1,-1,0, -1,0,-2,-1, 1,2,0,1, 0,1,-1,0};
  float c0 = 0.f, ca = 0.f, cb = 0.f, cab = 0.f;
#pragma unroll
  for (int i = 0; i < 16; ++i) {
    c0 += p[i] * GC[i]; ca += p[i] * GA[i];
    cb += p[i] * GB[i]; cab += p[i] * GAB[i];
  }
  coef[o] = make_float4(c0 * inv, ca * inv, cb * inv, cab * inv);
  pidx[o] = (uint32_t)idx_a[o] | ((uint32_t)idx_b[o] << 16);
}

// 2-row affine eval from one packed bf16-pair of a and b; returns {lo-row, hi-row}
__device__ __forceinline__ float2 eval2(float4 c, uint32_t ga, uint32_t gb) {
  const float a0 = bf_lo(ga), b0 = bf_lo(gb);
  const float a1 = bf_hi(ga), b1 = bf_hi(gb);
  float2 r;
  r.x = fmaf(fmaf(c.w, a0, c.z), b0, fmaf(c.y, a0, c.x));
  r.y = fmaf(fmaf(c.w, a1, c.z), b1, fmaf(c.y, a1, c.x));
  return r;
}

__global__ __launch_bounds__(THREADS)
void logic_main(const float* __restrict__ x,
                const float4* __restrict__ coef,
                const uint32_t* __restrict__ pidx,
                float* __restrict__ out) {
  // 4-row packed: xq[i] = { bf(r0[i]) | bf(r1[i])<<16 , bf(r2[i]) | bf(r3[i])<<16 }
  // one ds_read_b64 per gathered input serves all 4 rows.  64 KB -> 2 blocks/CU
  __shared__ u32x2 xq[IN_DIM];

  const int t  = threadIdx.x;
  const int b0 = blockIdx.x * RPB;

  const f32x4* __restrict__ r0 =
      reinterpret_cast<const f32x4*>(x + (size_t)(b0 + 0) * IN_DIM);
  const f32x4* __restrict__ r1 =
      reinterpret_cast<const f32x4*>(x + (size_t)(b0 + 1) * IN_DIM);
  const f32x4* __restrict__ r2 =
      reinterpret_cast<const f32x4*>(x + (size_t)(b0 + 2) * IN_DIM);
  const f32x4* __restrict__ r3 =
      reinterpret_cast<const f32x4*>(x + (size_t)(b0 + 3) * IN_DIM);

  // prefetch chunk-0 operands (hide L2 latency under staging)
  int o0 = t * OPT;
  int4   pi = *reinterpret_cast<const int4*>(pidx + o0);
  float4 c0 = coef[o0 + 0], c1 = coef[o0 + 1],
         c2 = coef[o0 + 2], c3 = coef[o0 + 3];

  // ---- stage 4 rows, 4-row-packed ----
#pragma unroll
  for (int s = 0; s < SSTEPS; ++s) {
    const int q = s * THREADS + t;                  // f32x4 index (elems 4q..4q+3)
    f32x4 a = r0[q], b = r1[q], c = r2[q], d = r3[q];
    u32x2 p0, p1, p2, p3;
    p0.x = pack_bf(a.x, b.x); p0.y = pack_bf(c.x, d.x);
    p1.x = pack_bf(a.y, b.y); p1.y = pack_bf(c.y, d.y);
    p2.x = pack_bf(a.z, b.z); p2.y = pack_bf(c.z, d.z);
    p3.x = pack_bf(a.w, b.w); p3.y = pack_bf(c.w, d.w);
    xq[4 * q + 0] = p0;
    xq[4 * q + 1] = p1;
    xq[4 * q + 2] = p2;
    xq[4 * q + 3] = p3;
  }
  __syncthreads();

#pragma unroll 2
  for (int ch = 0; ch < CHUNKS; ++ch) {
    const int o = ch * (THREADS * OPT) + t * OPT;

    const uint32_t i0a = (uint32_t)pi.x & 0xffffu, i0b = (uint32_t)pi.x >> 16;
    const uint32_t i1a = (uint32_t)pi.y & 0xffffu, i1b = (uint32_t)pi.y >> 16;
    const uint32_t i2a = (uint32_t)pi.z & 0xffffu, i2b = (uint32_t)pi.z >> 16;
    const uint32_t i3a = (uint32_t)pi.w & 0xffffu, i3b = (uint32_t)pi.w >> 16;

    // 8 ds_read_b64 gathers: each serves 4 rows
    const u32x2 g0a = xq[i0a], g0b = xq[i0b];
    const u32x2 g1a = xq[i1a], g1b = xq[i1b];
    const u32x2 g2a = xq[i2a], g2b = xq[i2b];
    const u32x2 g3a = xq[i3a], g3b = xq[i3b];

    const float2 e0lo = eval2(c0, g0a.x, g0b.x), e0hi = eval2(c0, g0a.y, g0b.y);
    const float2 e1lo = eval2(c1, g1a.x, g1b.x), e1hi = eval2(c1, g1a.y, g1b.y);
    const float2 e2lo = eval2(c2, g2a.x, g2b.x), e2hi = eval2(c2, g2a.y, g2b.y);
    const float2 e3lo = eval2(c3, g3a.x, g3b.x), e3hi = eval2(c3, g3a.y, g3b.y);

    f32x4 res0, res1, res2, res3;
    res0.x = e0lo.x; res0.y = e1lo.x; res0.z = e2lo.x; res0.w = e3lo.x;
    res1.x = e0lo.y; res1.y = e1lo.y; res1.z = e2lo.y; res1.w = e3lo.y;
    res2.x = e0hi.x; res2.y = e1hi.x; res2.z = e2hi.x; res2.w = e3hi.x;
    res3.x = e0hi.y; res3.y = e1hi.y; res3.z = e2hi.y; res3.w = e3hi.y;

    // prefetch next chunk's operands before the stores
    if (ch + 1 < CHUNKS) {
      const int on = o + THREADS * OPT;
      pi = *reinterpret_cast<const int4*>(pidx + on);
      c0 = coef[on + 0]; c1 = coef[on + 1];
      c2 = coef[on + 2]; c3 = coef[on + 3];
    }

    *reinterpret_cast<f32x4*>(out + (size_t)(b0 + 0) * OUT_DIM + o) = res0;
    *reinterpret_cast<f32x4*>(out + (size_t)(b0 + 1) * OUT_DIM + o) = res1;
    *reinterpret_cast<f32x4*>(out + (size_t)(b0 + 2) * OUT_DIM + o) = res2;
    *reinterpret_cast<f32x4*>(out + (size_t)(b0 + 3) * OUT_DIM + o) = res3;
  }
}

extern "C" void kernel_launch(void* const* d_in, const int* in_sizes, int n_in,
                              void* d_out, int out_size, void* d_ws, size_t ws_size,
                              hipStream_t stream) {
  const float* x       = (const float*)d_in[0];
  const float* weights = (const float*)d_in[1];
  const int*   idx_a   = (const int*)d_in[2];
  const int*   idx_b   = (const int*)d_in[3];
  float*       out     = (float*)d_out;

  float4*   coef = (float4*)d_ws;                                   // 256 KB
  uint32_t* pidx = (uint32_t*)((char*)d_ws + (size_t)OUT_DIM * 16); // +64 KB

  coef_kernel<<<OUT_DIM / 64, 64, 0, stream>>>(weights, idx_a, idx_b, coef, pidx);
  logic_main<<<NBLK, THREADS, 0, stream>>>(x, coef, pidx, out);
}